// Round 19
// baseline (42.892 us; speedup 1.0000x reference)
//
#include <hip/hip_runtime.h>
#include <hip/hip_fp16.h>
#include <float.h>
#include <math.h>

#define PPIL   40000
#define NPTS   32
#define COUT   64
#define PPB    32              // pillars per main block
#define NBLK_M 1250            // main blocks (PPIL / PPB)
#define PSTRIDE 132            // floats per pillar slot (33 float4: bank spread)
#define NSB_F  16              // stats reducer blocks
#define NFB    625             // final blocks (x1024 threads = 640000 float4)

// MEASUREMENT ROUND: pfn_main is launched TWICE (idempotent) so that
// dur_us = base(28.6) + T_main. This localizes the unexplained ~22 us.

__device__ __forceinline__ float shfl_xor_f(float v, int m) {
    return __shfl_xor(v, m, 64);
}

// ===========================================================================
// Kernel A (R12-proven optimum, byte-identical).
// ===========================================================================
__global__ __launch_bounds__(256) void pfn_main(
    const float* __restrict__ features, const int* __restrict__ num_voxels,
    const int* __restrict__ coors, const float* __restrict__ linear_w,
    __half* __restrict__ rawh, float* __restrict__ partials)
{
    __shared__ float lds_f[PPB * PSTRIDE];    // 16.9 KB staging
    __shared__ float lds_pc[PPB][12];         // {mx,my,mz,ax,by,nvf,Fm0..3}
    __shared__ float lds_w[64 * 9];           // {g0,g1,g2,g3,w4..w8}
    __shared__ float lds_red[4][128];

    const int tid = threadIdx.x;   // 0..255
    const int bid = blockIdx.x;
    const int pb  = bid * PPB;

    // ---- weight prep (threads 0..63) ----
    if (tid < 64) {
        const float* wr = linear_w + tid * 9;
        const float w0 = wr[0], w1 = wr[1], w2 = wr[2], w3 = wr[3], w4 = wr[4];
        const float w5 = wr[5], w6 = wr[6], w7 = wr[7], w8 = wr[8];
        float* dw = &lds_w[tid * 9];
        dw[0] = w0 + w4 + w7;
        dw[1] = w1 + w5 + w8;
        dw[2] = w2 + w6;
        dw[3] = w3;
        dw[4] = w4; dw[5] = w5; dw[6] = w6; dw[7] = w7; dw[8] = w8;
    }

    // ---- stage + pillar sums: thread (pl = tid>>3, sub = tid&7), 4 pts ----
    {
        const int pl  = tid >> 3, sub = tid & 7;
        const int p   = pb + pl;
        const int nvi = num_voxels[p];
        float sx = 0.f, sy = 0.f, sz = 0.f;
        float t0 = 0.f, t1 = 0.f, t2 = 0.f, t3 = 0.f;
        #pragma unroll
        for (int i = 0; i < 4; ++i) {
            const int n = sub + 8 * i;
            const float4 f = *(const float4*)(features + ((size_t)p * NPTS + n) * 4);
            *(float4*)&lds_f[pl * PSTRIDE + n * 4] = f;
            sx += f.x; sy += f.y; sz += f.z;
            const float m = (n < nvi) ? 1.0f : 0.0f;
            t0 = fmaf(f.x, m, t0); t1 = fmaf(f.y, m, t1);
            t2 = fmaf(f.z, m, t2); t3 = fmaf(f.w, m, t3);
        }
        #pragma unroll
        for (int m = 1; m <= 4; m <<= 1) {
            sx += shfl_xor_f(sx, m); sy += shfl_xor_f(sy, m); sz += shfl_xor_f(sz, m);
            t0 += shfl_xor_f(t0, m); t1 += shfl_xor_f(t1, m);
            t2 += shfl_xor_f(t2, m); t3 += shfl_xor_f(t3, m);
        }
        if (sub == 0) {
            const float nvf = (float)nvi;
            const float inv = 1.0f / nvf;
            float* pc = lds_pc[pl];
            pc[0] = sx * inv;
            pc[1] = sy * inv;
            pc[2] = sz * inv;
            pc[3] = (float)coors[p * 4 + 3] * 0.2f + 0.1f;     // ax
            pc[4] = (float)coors[p * 4 + 2] * 0.2f - 39.9f;    // by
            pc[5] = nvf;
            pc[6] = t0; pc[7] = t1; pc[8] = t2; pc[9] = t3;
        }
    }
    __syncthreads();

    // ---- phase B: lane = channel, wave per pillar ----
    const int w    = tid >> 6;    // wave 0..3
    const int lane = tid & 63;    // channel u

    const float* wp = &lds_w[lane * 9];
    const float g0 = wp[0], g1 = wp[1], g2 = wp[2], g3 = wp[3];
    const float w4 = wp[4], w5 = wp[5], w6 = wp[6], w7 = wp[7], w8 = wp[8];

    float s1acc = 0.0f, s2acc = 0.0f;

    #pragma unroll
    for (int i = 0; i < 8; ++i) {
        const int pl = w * 8 + i;
        const float* pc = lds_pc[pl];          // wave-uniform broadcast reads
        const float mxp = pc[0], myp = pc[1], mzp = pc[2];
        const float axp = pc[3], byp = pc[4], nvf = pc[5];
        const float Fm0 = pc[6], Fm1 = pc[7], Fm2 = pc[8], Fm3 = pc[9];
        const int   nvi = (int)nvf;

        float cc = -(w4 * mxp + w5 * myp + w6 * mzp + w7 * axp + w8 * byp);

        float s2 = 0.0f, mx = -FLT_MAX;
        const float4* fb = (const float4*)&lds_f[pl * PSTRIDE];
        int n = 0;
        for (; n + 2 <= nvi; n += 2) {         // exact-nv trip, 2-deep ILP
            const float4 fa = fb[n];
            const float4 fc = fb[n + 1];
            float xa = fmaf(g0, fa.x, cc);
            xa = fmaf(g1, fa.y, xa);
            xa = fmaf(g2, fa.z, xa);
            xa = fmaf(g3, fa.w, xa);
            float xb = fmaf(g0, fc.x, cc);
            xb = fmaf(g1, fc.y, xb);
            xb = fmaf(g2, fc.z, xb);
            xb = fmaf(g3, fc.w, xb);
            s2 = fmaf(xa, xa, s2);
            s2 = fmaf(xb, xb, s2);
            mx = fmaxf(mx, fmaxf(xa, xb));
        }
        if (n < nvi) {
            const float4 fa = fb[n];
            float xa = fmaf(g0, fa.x, cc);
            xa = fmaf(g1, fa.y, xa);
            xa = fmaf(g2, fa.z, xa);
            xa = fmaf(g3, fa.w, xa);
            s2 = fmaf(xa, xa, s2);
            mx = fmaxf(mx, xa);
        }
        if (nvi < NPTS) mx = fmaxf(mx, 0.0f);  // masked rows are exact zeros

        // factored s1: g.Fm + nv*cc
        float d = g0 * Fm0;
        d = fmaf(g1, Fm1, d);
        d = fmaf(g2, Fm2, d);
        d = fmaf(g3, Fm3, d);
        s1acc += fmaf(nvf, cc, d);
        s2acc += s2;

        rawh[(size_t)(pb + pl) * COUT + lane] = __float2half(mx);
    }

    // ---- cross-wave s1/s2 reduce -> partials[bid][128] ----
    lds_red[w][lane]      = s1acc;
    lds_red[w][64 + lane] = s2acc;
    __syncthreads();
    if (tid < 128) {
        const float acc = lds_red[0][tid] + lds_red[1][tid] +
                          lds_red[2][tid] + lds_red[3][tid];
        partials[bid * 128 + tid] = acc;       // t<64: s1[u=t], t>=64: s2
    }
}

// ===========================================================================
// Kernel B: 16 blocks reduce partials rows (double, float4 ILP) -> partials2.
// ===========================================================================
__global__ __launch_bounds__(1024) void pfn_stats16(
    const float* __restrict__ partials, float* __restrict__ partials2)
{
    __shared__ double red[32][128];
    const int t = threadIdx.x, b = blockIdx.x;
    const int col4 = t & 31, j = t >> 5;
    const float4* p4 = (const float4*)partials;

    double a0 = 0.0, a1 = 0.0, a2 = 0.0, a3 = 0.0;
    #pragma unroll
    for (int i = 0; i < 3; ++i) {              // covers rows 0..1249
        const int r = b + NSB_F * (j + 32 * i);
        if (r < NBLK_M) {
            const float4 v = p4[r * 32 + col4];
            a0 += (double)v.x; a1 += (double)v.y;
            a2 += (double)v.z; a3 += (double)v.w;
        }
    }
    red[j][col4 * 4 + 0] = a0;
    red[j][col4 * 4 + 1] = a1;
    red[j][col4 * 4 + 2] = a2;
    red[j][col4 * 4 + 3] = a3;
    __syncthreads();
    if (t < 128) {
        double s = 0.0;
        #pragma unroll
        for (int jj = 0; jj < 32; ++jj) s += red[jj][t];
        partials2[b * 128 + t] = (float)s;
    }
}

// ===========================================================================
// Kernel C: 625 blocks x 1024 threads. Combine partials2 (8KB, L2-hot),
// fp32 finalize, then out = relu(rawh_fp16 * scale + bias) (coalesced).
// ===========================================================================
__global__ __launch_bounds__(1024) void pfn_final(
    const float* __restrict__ partials2, const float* __restrict__ gamma,
    const float* __restrict__ beta, const __half* __restrict__ rawh,
    float* __restrict__ out)
{
    __shared__ double red[128];
    __shared__ float  sb[128];
    const int t = threadIdx.x;
    if (t < 128) {
        double s = 0.0;
        #pragma unroll
        for (int b = 0; b < NSB_F; ++b) s += (double)partials2[b * 128 + t];
        red[t] = s;
    }
    __syncthreads();
    if (t < 64) {
        const float s1 = (float)red[t];
        const float s2 = (float)red[64 + t];
        const float invPN = 1.0f / ((float)PPIL * (float)NPTS);
        const float mean  = s1 * invPN;
        const float var   = fmaf(-mean, mean, s2 * invPN);
        const float scale = gamma[t] * rsqrtf(var + 1e-3f);
        sb[t]      = scale;
        sb[64 + t] = fmaf(-mean, scale, beta[t]);
    }
    __syncthreads();

    const int i  = blockIdx.x * 1024 + t;    // 640000 = 625*1024
    const int u0 = (i & 15) * 4;             // 4 consecutive channels
    const uint2 pk = *(const uint2*)(rawh + (size_t)i * 4);
    const __half2 h01 = *(const __half2*)&pk.x;
    const __half2 h23 = *(const __half2*)&pk.y;
    float4 v;
    v.x = fmaxf(fmaf(__low2float(h01),  sb[u0 + 0], sb[64 + u0 + 0]), 0.0f);
    v.y = fmaxf(fmaf(__high2float(h01), sb[u0 + 1], sb[64 + u0 + 1]), 0.0f);
    v.z = fmaxf(fmaf(__low2float(h23),  sb[u0 + 2], sb[64 + u0 + 2]), 0.0f);
    v.w = fmaxf(fmaf(__high2float(h23), sb[u0 + 3], sb[64 + u0 + 3]), 0.0f);
    ((float4*)out)[i] = v;
}

// ---------------------------------------------------------------------------
extern "C" void kernel_launch(void* const* d_in, const int* in_sizes, int n_in,
                              void* d_out, int out_size, void* d_ws, size_t ws_size,
                              hipStream_t stream) {
    const float* features   = (const float*)d_in[0];
    const int*   num_voxels = (const int*)d_in[1];
    const int*   coors      = (const int*)d_in[2];
    const float* linear_w   = (const float*)d_in[3];
    const float* gamma      = (const float*)d_in[4];
    const float* beta       = (const float*)d_in[5];

    float*  out       = (float*)d_out;
    float*  wsf       = (float*)d_ws;
    float*  partials  = wsf;                    // NBLK_M*128 = 160K floats
    float*  partials2 = wsf + NBLK_M * 128;     // NSB_F*128 floats
    __half* rawh      = (__half*)(wsf + (1 << 20));  // 5.12 MB at +4MB offset

    // MEASUREMENT: main launched twice (idempotent) -> dur = base + T_main.
    pfn_main<<<NBLK_M, 256, 0, stream>>>(features, num_voxels, coors,
                                         linear_w, rawh, partials);
    pfn_main<<<NBLK_M, 256, 0, stream>>>(features, num_voxels, coors,
                                         linear_w, rawh, partials);
    pfn_stats16<<<NSB_F, 1024, 0, stream>>>(partials, partials2);
    pfn_final<<<NFB, 1024, 0, stream>>>(partials2, gamma, beta, rawh, out);
}

// Round 20
// 35.628 us; speedup vs baseline: 1.2039x; 1.2039x over previous
//
#include <hip/hip_runtime.h>
#include <hip/hip_fp16.h>
#include <float.h>
#include <math.h>

#define PPIL   40000
#define NPTS   32
#define COUT   64
#define PPB    32              // pillars per main block
#define NBLK_M 1250            // main blocks (PPIL / PPB)
#define PSTRIDE 132            // floats per pillar slot (33 float4: bank spread)
#define NSB_F  16              // stats reducer blocks
#define NFB    625             // final blocks (x1024 threads = 640000 float4)

__device__ __forceinline__ float shfl_xor_f(float v, int m) {
    return __shfl_xor(v, m, 64);
}

// ===========================================================================
// Kernel A (R12-proven optimum, unchanged except counter reset by block 0):
// 1250 blocks x 256 threads, 32 pillars each.
// ===========================================================================
__global__ __launch_bounds__(256) void pfn_main(
    const float* __restrict__ features, const int* __restrict__ num_voxels,
    const int* __restrict__ coors, const float* __restrict__ linear_w,
    __half* __restrict__ rawh, float* __restrict__ partials,
    int* __restrict__ counter)
{
    __shared__ float lds_f[PPB * PSTRIDE];    // 16.9 KB staging
    __shared__ float lds_pc[PPB][12];         // {mx,my,mz,ax,by,nvf,Fm0..3}
    __shared__ float lds_w[64 * 9];           // {g0,g1,g2,g3,w4..w8}
    __shared__ float lds_red[4][128];

    const int tid = threadIdx.x;   // 0..255
    const int bid = blockIdx.x;
    const int pb  = bid * PPB;

    if (bid == 0 && tid == 0) *counter = 0;   // ticket reset (stream order
                                              // guarantees visibility to B)

    // ---- weight prep (threads 0..63) ----
    if (tid < 64) {
        const float* wr = linear_w + tid * 9;
        const float w0 = wr[0], w1 = wr[1], w2 = wr[2], w3 = wr[3], w4 = wr[4];
        const float w5 = wr[5], w6 = wr[6], w7 = wr[7], w8 = wr[8];
        float* dw = &lds_w[tid * 9];
        dw[0] = w0 + w4 + w7;
        dw[1] = w1 + w5 + w8;
        dw[2] = w2 + w6;
        dw[3] = w3;
        dw[4] = w4; dw[5] = w5; dw[6] = w6; dw[7] = w7; dw[8] = w8;
    }

    // ---- stage + pillar sums: thread (pl = tid>>3, sub = tid&7), 4 pts ----
    {
        const int pl  = tid >> 3, sub = tid & 7;
        const int p   = pb + pl;
        const int nvi = num_voxels[p];
        float sx = 0.f, sy = 0.f, sz = 0.f;
        float t0 = 0.f, t1 = 0.f, t2 = 0.f, t3 = 0.f;
        #pragma unroll
        for (int i = 0; i < 4; ++i) {
            const int n = sub + 8 * i;
            const float4 f = *(const float4*)(features + ((size_t)p * NPTS + n) * 4);
            *(float4*)&lds_f[pl * PSTRIDE + n * 4] = f;
            sx += f.x; sy += f.y; sz += f.z;
            const float m = (n < nvi) ? 1.0f : 0.0f;
            t0 = fmaf(f.x, m, t0); t1 = fmaf(f.y, m, t1);
            t2 = fmaf(f.z, m, t2); t3 = fmaf(f.w, m, t3);
        }
        #pragma unroll
        for (int m = 1; m <= 4; m <<= 1) {
            sx += shfl_xor_f(sx, m); sy += shfl_xor_f(sy, m); sz += shfl_xor_f(sz, m);
            t0 += shfl_xor_f(t0, m); t1 += shfl_xor_f(t1, m);
            t2 += shfl_xor_f(t2, m); t3 += shfl_xor_f(t3, m);
        }
        if (sub == 0) {
            const float nvf = (float)nvi;
            const float inv = 1.0f / nvf;
            float* pc = lds_pc[pl];
            pc[0] = sx * inv;
            pc[1] = sy * inv;
            pc[2] = sz * inv;
            pc[3] = (float)coors[p * 4 + 3] * 0.2f + 0.1f;     // ax
            pc[4] = (float)coors[p * 4 + 2] * 0.2f - 39.9f;    // by
            pc[5] = nvf;
            pc[6] = t0; pc[7] = t1; pc[8] = t2; pc[9] = t3;
        }
    }
    __syncthreads();

    // ---- phase B: lane = channel, wave per pillar ----
    const int w    = tid >> 6;    // wave 0..3
    const int lane = tid & 63;    // channel u

    const float* wp = &lds_w[lane * 9];
    const float g0 = wp[0], g1 = wp[1], g2 = wp[2], g3 = wp[3];
    const float w4 = wp[4], w5 = wp[5], w6 = wp[6], w7 = wp[7], w8 = wp[8];

    float s1acc = 0.0f, s2acc = 0.0f;

    #pragma unroll
    for (int i = 0; i < 8; ++i) {
        const int pl = w * 8 + i;
        const float* pc = lds_pc[pl];          // wave-uniform broadcast reads
        const float mxp = pc[0], myp = pc[1], mzp = pc[2];
        const float axp = pc[3], byp = pc[4], nvf = pc[5];
        const float Fm0 = pc[6], Fm1 = pc[7], Fm2 = pc[8], Fm3 = pc[9];
        const int   nvi = (int)nvf;

        float cc = -(w4 * mxp + w5 * myp + w6 * mzp + w7 * axp + w8 * byp);

        float s2 = 0.0f, mx = -FLT_MAX;
        const float4* fb = (const float4*)&lds_f[pl * PSTRIDE];
        int n = 0;
        for (; n + 2 <= nvi; n += 2) {         // exact-nv trip, 2-deep ILP
            const float4 fa = fb[n];
            const float4 fc = fb[n + 1];
            float xa = fmaf(g0, fa.x, cc);
            xa = fmaf(g1, fa.y, xa);
            xa = fmaf(g2, fa.z, xa);
            xa = fmaf(g3, fa.w, xa);
            float xb = fmaf(g0, fc.x, cc);
            xb = fmaf(g1, fc.y, xb);
            xb = fmaf(g2, fc.z, xb);
            xb = fmaf(g3, fc.w, xb);
            s2 = fmaf(xa, xa, s2);
            s2 = fmaf(xb, xb, s2);
            mx = fmaxf(mx, fmaxf(xa, xb));
        }
        if (n < nvi) {
            const float4 fa = fb[n];
            float xa = fmaf(g0, fa.x, cc);
            xa = fmaf(g1, fa.y, xa);
            xa = fmaf(g2, fa.z, xa);
            xa = fmaf(g3, fa.w, xa);
            s2 = fmaf(xa, xa, s2);
            mx = fmaxf(mx, xa);
        }
        if (nvi < NPTS) mx = fmaxf(mx, 0.0f);  // masked rows are exact zeros

        // factored s1: g.Fm + nv*cc
        float d = g0 * Fm0;
        d = fmaf(g1, Fm1, d);
        d = fmaf(g2, Fm2, d);
        d = fmaf(g3, Fm3, d);
        s1acc += fmaf(nvf, cc, d);
        s2acc += s2;

        rawh[(size_t)(pb + pl) * COUT + lane] = __float2half(mx);
    }

    // ---- cross-wave s1/s2 reduce -> partials[bid][128] ----
    lds_red[w][lane]      = s1acc;
    lds_red[w][64 + lane] = s2acc;
    __syncthreads();
    if (tid < 128) {
        const float acc = lds_red[0][tid] + lds_red[1][tid] +
                          lds_red[2][tid] + lds_red[3][tid];
        partials[bid * 128 + tid] = acc;       // t<64: s1[u=t], t>=64: s2
    }
}

// ===========================================================================
// Kernel B: 16 blocks reduce partials rows (double, float4 ILP) -> partials2;
// the LAST block (device-scope ticket) combines the 16 rows and finalizes
// scale/bias -> sb[128]. Deterministic: fixed-order sum by one block.
// ===========================================================================
__global__ __launch_bounds__(1024) void pfn_stats16(
    const float* __restrict__ partials, const float* __restrict__ gamma,
    const float* __restrict__ beta, float* __restrict__ partials2,
    float* __restrict__ sb_g, int* __restrict__ counter)
{
    __shared__ double red[32][128];
    __shared__ int   is_last;
    __shared__ float fs[128];
    const int t = threadIdx.x, b = blockIdx.x;
    const int col4 = t & 31, j = t >> 5;
    const float4* p4 = (const float4*)partials;

    double a0 = 0.0, a1 = 0.0, a2 = 0.0, a3 = 0.0;
    #pragma unroll
    for (int i = 0; i < 3; ++i) {              // covers rows 0..1249
        const int r = b + NSB_F * (j + 32 * i);
        if (r < NBLK_M) {
            const float4 v = p4[r * 32 + col4];
            a0 += (double)v.x; a1 += (double)v.y;
            a2 += (double)v.z; a3 += (double)v.w;
        }
    }
    red[j][col4 * 4 + 0] = a0;
    red[j][col4 * 4 + 1] = a1;
    red[j][col4 * 4 + 2] = a2;
    red[j][col4 * 4 + 3] = a3;
    __syncthreads();
    if (t < 128) {
        double s = 0.0;
        #pragma unroll
        for (int jj = 0; jj < 32; ++jj) s += red[jj][t];
        partials2[b * 128 + t] = (float)s;
    }
    __syncthreads();
    if (t == 0) {
        __threadfence();                        // publish partials2 row
        is_last = (atomicAdd(counter, 1) == NSB_F - 1);
    }
    __syncthreads();

    if (is_last) {                              // block-uniform branch
        __threadfence();                        // acquire others' rows
        if (t < 128) {
            const volatile float* vp = (const volatile float*)partials2;
            float s = 0.0f;
            #pragma unroll
            for (int bb = 0; bb < NSB_F; ++bb) s += vp[bb * 128 + t];
            fs[t] = s;
        }
        __syncthreads();
        if (t < 64) {
            const float s1 = fs[t];
            const float s2 = fs[64 + t];
            const float invPN = 1.0f / ((float)PPIL * (float)NPTS);
            const float mean  = s1 * invPN;
            const float var   = fmaf(-mean, mean, s2 * invPN);
            const float scale = gamma[t] * rsqrtf(var + 1e-3f);
            sb_g[t]      = scale;
            sb_g[64 + t] = fmaf(-mean, scale, beta[t]);
        }
    }
}

// ===========================================================================
// Kernel C: 625 blocks x 1024 threads, PURE STREAMING: sb (512B) -> LDS once
// per block, then out = relu(rawh_fp16 * scale + bias), coalesced.
// ===========================================================================
__global__ __launch_bounds__(1024) void pfn_final(
    const float* __restrict__ sb_g, const __half* __restrict__ rawh,
    float* __restrict__ out)
{
    __shared__ float sb[128];
    const int t = threadIdx.x;
    if (t < 128) sb[t] = sb_g[t];
    __syncthreads();

    const int i  = blockIdx.x * 1024 + t;    // 640000 = 625*1024
    const int u0 = (i & 15) * 4;             // 4 consecutive channels
    const uint2 pk = *(const uint2*)(rawh + (size_t)i * 4);
    const __half2 h01 = *(const __half2*)&pk.x;
    const __half2 h23 = *(const __half2*)&pk.y;
    float4 v;
    v.x = fmaxf(fmaf(__low2float(h01),  sb[u0 + 0], sb[64 + u0 + 0]), 0.0f);
    v.y = fmaxf(fmaf(__high2float(h01), sb[u0 + 1], sb[64 + u0 + 1]), 0.0f);
    v.z = fmaxf(fmaf(__low2float(h23),  sb[u0 + 2], sb[64 + u0 + 2]), 0.0f);
    v.w = fmaxf(fmaf(__high2float(h23), sb[u0 + 3], sb[64 + u0 + 3]), 0.0f);
    ((float4*)out)[i] = v;
}

// ---------------------------------------------------------------------------
extern "C" void kernel_launch(void* const* d_in, const int* in_sizes, int n_in,
                              void* d_out, int out_size, void* d_ws, size_t ws_size,
                              hipStream_t stream) {
    const float* features   = (const float*)d_in[0];
    const int*   num_voxels = (const int*)d_in[1];
    const int*   coors      = (const int*)d_in[2];
    const float* linear_w   = (const float*)d_in[3];
    const float* gamma      = (const float*)d_in[4];
    const float* beta       = (const float*)d_in[5];

    float*  out       = (float*)d_out;
    float*  wsf       = (float*)d_ws;
    float*  partials  = wsf;                         // NBLK_M*128 = 160K floats
    float*  partials2 = wsf + NBLK_M * 128;          // NSB_F*128 floats
    float*  sb_g      = partials2 + NSB_F * 128;     // 128 floats
    int*    counter   = (int*)(sb_g + 128);          // 1 int (reset by main)
    __half* rawh      = (__half*)(wsf + (1 << 20));  // 5.12 MB at +4MB offset

    pfn_main<<<NBLK_M, 256, 0, stream>>>(features, num_voxels, coors,
                                         linear_w, rawh, partials, counter);
    pfn_stats16<<<NSB_F, 1024, 0, stream>>>(partials, gamma, beta,
                                            partials2, sb_g, counter);
    pfn_final<<<NFB, 1024, 0, stream>>>(sb_g, rawh, out);
}

// Round 21
// 28.575 us; speedup vs baseline: 1.5010x; 1.2468x over previous
//
#include <hip/hip_runtime.h>
#include <hip/hip_fp16.h>
#include <float.h>
#include <math.h>

#define PPIL   40000
#define NPTS   32
#define COUT   64
#define PPB    32              // pillars per main block
#define NBLK_M 1250            // main blocks (PPIL / PPB)
#define PSTRIDE 132            // floats per pillar slot (33 float4: bank spread)
#define NSB_F  16              // stats reducer blocks
#define NFB    625             // final blocks (x1024 threads = 640000 float4)

__device__ __forceinline__ float shfl_xor_f(float v, int m) {
    return __shfl_xor(v, m, 64);
}

// ===========================================================================
// Kernel A (R12-proven optimum, 28.7 us total, reproduced 3x +-0.1):
// 1250 blocks x 256 threads, 32 pillars each.
// Stage (8 thr/pillar, 4 pts each, butterfly masks 1,2,4) -> lds_f + lds_pc.
// Phase B: lane = channel. Wave w handles pillars 8w..8w+7 sequentially;
// per pillar the loop runs its EXACT nv (no wave-max divergence waste),
// f[n] is a wave-uniform LDS broadcast, per-lane state is 9 weight regs.
// s1 factored; s2 in-loop; max clamped by 0 for masked rows.
// rawmax -> fp16 ws. partials[bid][128] per block.
// ===========================================================================
__global__ __launch_bounds__(256) void pfn_main(
    const float* __restrict__ features, const int* __restrict__ num_voxels,
    const int* __restrict__ coors, const float* __restrict__ linear_w,
    __half* __restrict__ rawh, float* __restrict__ partials)
{
    __shared__ float lds_f[PPB * PSTRIDE];    // 16.9 KB staging
    __shared__ float lds_pc[PPB][12];         // {mx,my,mz,ax,by,nvf,Fm0..3}
    __shared__ float lds_w[64 * 9];           // {g0,g1,g2,g3,w4..w8}
    __shared__ float lds_red[4][128];

    const int tid = threadIdx.x;   // 0..255
    const int bid = blockIdx.x;
    const int pb  = bid * PPB;

    // ---- weight prep (threads 0..63) ----
    if (tid < 64) {
        const float* wr = linear_w + tid * 9;
        const float w0 = wr[0], w1 = wr[1], w2 = wr[2], w3 = wr[3], w4 = wr[4];
        const float w5 = wr[5], w6 = wr[6], w7 = wr[7], w8 = wr[8];
        float* dw = &lds_w[tid * 9];
        dw[0] = w0 + w4 + w7;
        dw[1] = w1 + w5 + w8;
        dw[2] = w2 + w6;
        dw[3] = w3;
        dw[4] = w4; dw[5] = w5; dw[6] = w6; dw[7] = w7; dw[8] = w8;
    }

    // ---- stage + pillar sums: thread (pl = tid>>3, sub = tid&7), 4 pts ----
    {
        const int pl  = tid >> 3, sub = tid & 7;
        const int p   = pb + pl;
        const int nvi = num_voxels[p];
        float sx = 0.f, sy = 0.f, sz = 0.f;
        float t0 = 0.f, t1 = 0.f, t2 = 0.f, t3 = 0.f;
        #pragma unroll
        for (int i = 0; i < 4; ++i) {
            const int n = sub + 8 * i;
            const float4 f = *(const float4*)(features + ((size_t)p * NPTS + n) * 4);
            *(float4*)&lds_f[pl * PSTRIDE + n * 4] = f;
            sx += f.x; sy += f.y; sz += f.z;
            const float m = (n < nvi) ? 1.0f : 0.0f;
            t0 = fmaf(f.x, m, t0); t1 = fmaf(f.y, m, t1);
            t2 = fmaf(f.z, m, t2); t3 = fmaf(f.w, m, t3);
        }
        #pragma unroll
        for (int m = 1; m <= 4; m <<= 1) {
            sx += shfl_xor_f(sx, m); sy += shfl_xor_f(sy, m); sz += shfl_xor_f(sz, m);
            t0 += shfl_xor_f(t0, m); t1 += shfl_xor_f(t1, m);
            t2 += shfl_xor_f(t2, m); t3 += shfl_xor_f(t3, m);
        }
        if (sub == 0) {
            const float nvf = (float)nvi;
            const float inv = 1.0f / nvf;
            float* pc = lds_pc[pl];
            pc[0] = sx * inv;
            pc[1] = sy * inv;
            pc[2] = sz * inv;
            pc[3] = (float)coors[p * 4 + 3] * 0.2f + 0.1f;     // ax
            pc[4] = (float)coors[p * 4 + 2] * 0.2f - 39.9f;    // by
            pc[5] = nvf;
            pc[6] = t0; pc[7] = t1; pc[8] = t2; pc[9] = t3;
        }
    }
    __syncthreads();

    // ---- phase B: lane = channel, wave per pillar ----
    const int w    = tid >> 6;    // wave 0..3
    const int lane = tid & 63;    // channel u

    const float* wp = &lds_w[lane * 9];
    const float g0 = wp[0], g1 = wp[1], g2 = wp[2], g3 = wp[3];
    const float w4 = wp[4], w5 = wp[5], w6 = wp[6], w7 = wp[7], w8 = wp[8];

    float s1acc = 0.0f, s2acc = 0.0f;

    #pragma unroll
    for (int i = 0; i < 8; ++i) {
        const int pl = w * 8 + i;
        const float* pc = lds_pc[pl];          // wave-uniform broadcast reads
        const float mxp = pc[0], myp = pc[1], mzp = pc[2];
        const float axp = pc[3], byp = pc[4], nvf = pc[5];
        const float Fm0 = pc[6], Fm1 = pc[7], Fm2 = pc[8], Fm3 = pc[9];
        const int   nvi = (int)nvf;

        float cc = -(w4 * mxp + w5 * myp + w6 * mzp + w7 * axp + w8 * byp);

        float s2 = 0.0f, mx = -FLT_MAX;
        const float4* fb = (const float4*)&lds_f[pl * PSTRIDE];
        int n = 0;
        for (; n + 2 <= nvi; n += 2) {         // exact-nv trip, 2-deep ILP
            const float4 fa = fb[n];
            const float4 fc = fb[n + 1];
            float xa = fmaf(g0, fa.x, cc);
            xa = fmaf(g1, fa.y, xa);
            xa = fmaf(g2, fa.z, xa);
            xa = fmaf(g3, fa.w, xa);
            float xb = fmaf(g0, fc.x, cc);
            xb = fmaf(g1, fc.y, xb);
            xb = fmaf(g2, fc.z, xb);
            xb = fmaf(g3, fc.w, xb);
            s2 = fmaf(xa, xa, s2);
            s2 = fmaf(xb, xb, s2);
            mx = fmaxf(mx, fmaxf(xa, xb));
        }
        if (n < nvi) {
            const float4 fa = fb[n];
            float xa = fmaf(g0, fa.x, cc);
            xa = fmaf(g1, fa.y, xa);
            xa = fmaf(g2, fa.z, xa);
            xa = fmaf(g3, fa.w, xa);
            s2 = fmaf(xa, xa, s2);
            mx = fmaxf(mx, xa);
        }
        if (nvi < NPTS) mx = fmaxf(mx, 0.0f);  // masked rows are exact zeros

        // factored s1: g.Fm + nv*cc
        float d = g0 * Fm0;
        d = fmaf(g1, Fm1, d);
        d = fmaf(g2, Fm2, d);
        d = fmaf(g3, Fm3, d);
        s1acc += fmaf(nvf, cc, d);
        s2acc += s2;

        rawh[(size_t)(pb + pl) * COUT + lane] = __float2half(mx);
    }

    // ---- cross-wave s1/s2 reduce -> partials[bid][128] ----
    lds_red[w][lane]      = s1acc;
    lds_red[w][64 + lane] = s2acc;
    __syncthreads();
    if (tid < 128) {
        const float acc = lds_red[0][tid] + lds_red[1][tid] +
                          lds_red[2][tid] + lds_red[3][tid];
        partials[bid * 128 + tid] = acc;       // t<64: s1[u=t], t>=64: s2
    }
}

// ===========================================================================
// Kernel B: 16 blocks reduce partials rows (double, float4 ILP) -> partials2.
// ===========================================================================
__global__ __launch_bounds__(1024) void pfn_stats16(
    const float* __restrict__ partials, float* __restrict__ partials2)
{
    __shared__ double red[32][128];
    const int t = threadIdx.x, b = blockIdx.x;
    const int col4 = t & 31, j = t >> 5;
    const float4* p4 = (const float4*)partials;

    double a0 = 0.0, a1 = 0.0, a2 = 0.0, a3 = 0.0;
    #pragma unroll
    for (int i = 0; i < 3; ++i) {              // covers rows 0..1249
        const int r = b + NSB_F * (j + 32 * i);
        if (r < NBLK_M) {
            const float4 v = p4[r * 32 + col4];
            a0 += (double)v.x; a1 += (double)v.y;
            a2 += (double)v.z; a3 += (double)v.w;
        }
    }
    red[j][col4 * 4 + 0] = a0;
    red[j][col4 * 4 + 1] = a1;
    red[j][col4 * 4 + 2] = a2;
    red[j][col4 * 4 + 3] = a3;
    __syncthreads();
    if (t < 128) {
        double s = 0.0;
        #pragma unroll
        for (int jj = 0; jj < 32; ++jj) s += red[jj][t];
        partials2[b * 128 + t] = (float)s;
    }
}

// ===========================================================================
// Kernel C: 625 blocks x 1024 threads. Combine partials2 (8KB, L2-hot),
// fp32 finalize, then out = relu(rawh_fp16 * scale + bias) (coalesced).
// ===========================================================================
__global__ __launch_bounds__(1024) void pfn_final(
    const float* __restrict__ partials2, const float* __restrict__ gamma,
    const float* __restrict__ beta, const __half* __restrict__ rawh,
    float* __restrict__ out)
{
    __shared__ double red[128];
    __shared__ float  sb[128];
    const int t = threadIdx.x;
    if (t < 128) {
        double s = 0.0;
        #pragma unroll
        for (int b = 0; b < NSB_F; ++b) s += (double)partials2[b * 128 + t];
        red[t] = s;
    }
    __syncthreads();
    if (t < 64) {
        const float s1 = (float)red[t];
        const float s2 = (float)red[64 + t];
        const float invPN = 1.0f / ((float)PPIL * (float)NPTS);
        const float mean  = s1 * invPN;
        const float var   = fmaf(-mean, mean, s2 * invPN);
        const float scale = gamma[t] * rsqrtf(var + 1e-3f);
        sb[t]      = scale;
        sb[64 + t] = fmaf(-mean, scale, beta[t]);
    }
    __syncthreads();

    const int i  = blockIdx.x * 1024 + t;    // 640000 = 625*1024
    const int u0 = (i & 15) * 4;             // 4 consecutive channels
    const uint2 pk = *(const uint2*)(rawh + (size_t)i * 4);
    const __half2 h01 = *(const __half2*)&pk.x;
    const __half2 h23 = *(const __half2*)&pk.y;
    float4 v;
    v.x = fmaxf(fmaf(__low2float(h01),  sb[u0 + 0], sb[64 + u0 + 0]), 0.0f);
    v.y = fmaxf(fmaf(__high2float(h01), sb[u0 + 1], sb[64 + u0 + 1]), 0.0f);
    v.z = fmaxf(fmaf(__low2float(h23),  sb[u0 + 2], sb[64 + u0 + 2]), 0.0f);
    v.w = fmaxf(fmaf(__high2float(h23), sb[u0 + 3], sb[64 + u0 + 3]), 0.0f);
    ((float4*)out)[i] = v;
}

// ---------------------------------------------------------------------------
extern "C" void kernel_launch(void* const* d_in, const int* in_sizes, int n_in,
                              void* d_out, int out_size, void* d_ws, size_t ws_size,
                              hipStream_t stream) {
    const float* features   = (const float*)d_in[0];
    const int*   num_voxels = (const int*)d_in[1];
    const int*   coors      = (const int*)d_in[2];
    const float* linear_w   = (const float*)d_in[3];
    const float* gamma      = (const float*)d_in[4];
    const float* beta       = (const float*)d_in[5];

    float*  out       = (float*)d_out;
    float*  wsf       = (float*)d_ws;
    float*  partials  = wsf;                    // NBLK_M*128 = 160K floats
    float*  partials2 = wsf + NBLK_M * 128;     // NSB_F*128 floats
    __half* rawh      = (__half*)(wsf + (1 << 20));  // 5.12 MB at +4MB offset

    pfn_main<<<NBLK_M, 256, 0, stream>>>(features, num_voxels, coors,
                                         linear_w, rawh, partials);
    pfn_stats16<<<NSB_F, 1024, 0, stream>>>(partials, partials2);
    pfn_final<<<NFB, 1024, 0, stream>>>(partials2, gamma, beta, rawh, out);
}